// Round 5
// baseline (265.934 us; speedup 1.0000x reference)
//
#include <hip/hip_runtime.h>
#include <stdint.h>

// B=16, CIN=512, COUT=128, H=W=64
#define NB    16
#define CIN   512
#define COUT  128
#define HW    4096
#define BN    128             // N-tile per block
#define BK    32              // K-tile per iteration
#define NIT   (CIN / BK)      // 16
// grid = 16 b x 32 n-tiles = 512 blocks x 512 thr = 2 blocks/CU

using bf16x8  = __attribute__((ext_vector_type(8))) __bf16;
using floatx4 = __attribute__((ext_vector_type(4))) float;

// RNE float -> bf16 bits (proven in previous session)
__device__ __forceinline__ unsigned short f2bf_bits(float f) {
    union { float f; unsigned u; } v; v.f = f;
    return (unsigned short)((v.u + 0x7fffu + ((v.u >> 16) & 1u)) >> 16);
}

// ---------------------------------------------------------------------------
// SINGLE fused kernel.
// A-fragments built in registers from weight*style, with weight/style regs
// prefetched ONE FULL ITERATION ahead (R3's fusion failed because it loaded
// and consumed weight within the same iteration = serial L2 latency).
// B path = R4's reg-staged pipeline: global->reg (256B coalesced), one
// fp32->bf16 convert per element, ds_write_b128 in MFMA fragment layout,
// B-fragment = 1 conflict-free ds_read_b128. B loads issued 2 iters ahead.
// All loads are register loads -> compiler inserts exact vmcnt waits; every
// consumed value is >=1 iteration old, so no wait ever stalls. The barrier
// needs only lgkmcnt(0) (publish ds_writes) -- no vmcnt drain anywhere.
// ---------------------------------------------------------------------------
__global__ __launch_bounds__(512, 4)
void modconv_fused_kernel(const float* __restrict__ x,
                          const float* __restrict__ style,
                          const float* __restrict__ weight,
                          float* __restrict__ out)
{
    __shared__ __align__(16) __bf16 Bfs[2][4 * 128 * 8];  // [kg][n][j] 2 x 8 KB

    const int tid  = threadIdx.x;
    const int lane = tid & 63;
    const int wave = tid >> 6;          // 0..7
    const int quad = lane >> 4;
    const int l15  = lane & 15;

    const int b  = blockIdx.x >> 5;
    const int n0 = (blockIdx.x & 31) * BN;

    float* outb = out + (size_t)b * COUT * HW + n0;

    const int wm = (wave & 1) * 64;     // wave tile 64(m) x 32(n)
    const int wn = (wave >> 1) * 32;

    // per-thread A sources: weight rows m = wm + tm*16 + l15, k-window
    // it*32 + quad*8 .. +7 ; style[b][same window]
    const float* wr0 = weight + (size_t)(wm + 0 * 16 + l15) * CIN + quad * 8;
    const float* wr1 = weight + (size_t)(wm + 1 * 16 + l15) * CIN + quad * 8;
    const float* wr2 = weight + (size_t)(wm + 2 * 16 + l15) * CIN + quad * 8;
    const float* wr3 = weight + (size_t)(wm + 3 * 16 + l15) * CIN + quad * 8;
    const float* sb  = style + (size_t)b * CIN + quad * 8;

    // B staging geometry: thread covers kg = tid>>7 (k-slab of 8), bn = tid&127
    const int kg = tid >> 7;            // 0..3
    const int bn = tid & 127;           // n within tile
    const float* xbn = x + (size_t)b * CIN * HW + (size_t)kg * 8 * HW + n0 + bn;

    floatx4 acc[4][2];
    #pragma unroll
    for (int i = 0; i < 4; ++i)
        #pragma unroll
        for (int j = 0; j < 2; ++j)
            acc[i][j] = (floatx4){0.f, 0.f, 0.f, 0.f};

    // weight/style prefetch registers (single set, refilled right after use)
    float4 sv0, sv1, w00, w01, w10, w11, w20, w21, w30, w31;
    // A fragments for the current tile
    bf16x8 af0, af1, af2, af3;
    float xa[8], xb[8];

#define WLOAD(T)                                                               \
    {                                                                          \
        const int ko = (T) * BK;                                               \
        sv0 = *(const float4*)(sb + ko);  sv1 = *(const float4*)(sb + ko + 4); \
        w00 = *(const float4*)(wr0 + ko); w01 = *(const float4*)(wr0 + ko + 4);\
        w10 = *(const float4*)(wr1 + ko); w11 = *(const float4*)(wr1 + ko + 4);\
        w20 = *(const float4*)(wr2 + ko); w21 = *(const float4*)(wr2 + ko + 4);\
        w30 = *(const float4*)(wr3 + ko); w31 = *(const float4*)(wr3 + ko + 4);\
    }

#define ABUILD()                                                               \
    {                                                                          \
        union { unsigned short us[8]; bf16x8 v; } p0, p1, p2, p3;              \
        p0.us[0] = f2bf_bits(w00.x * sv0.x); p0.us[1] = f2bf_bits(w00.y * sv0.y); \
        p0.us[2] = f2bf_bits(w00.z * sv0.z); p0.us[3] = f2bf_bits(w00.w * sv0.w); \
        p0.us[4] = f2bf_bits(w01.x * sv1.x); p0.us[5] = f2bf_bits(w01.y * sv1.y); \
        p0.us[6] = f2bf_bits(w01.z * sv1.z); p0.us[7] = f2bf_bits(w01.w * sv1.w); \
        p1.us[0] = f2bf_bits(w10.x * sv0.x); p1.us[1] = f2bf_bits(w10.y * sv0.y); \
        p1.us[2] = f2bf_bits(w10.z * sv0.z); p1.us[3] = f2bf_bits(w10.w * sv0.w); \
        p1.us[4] = f2bf_bits(w11.x * sv1.x); p1.us[5] = f2bf_bits(w11.y * sv1.y); \
        p1.us[6] = f2bf_bits(w11.z * sv1.z); p1.us[7] = f2bf_bits(w11.w * sv1.w); \
        p2.us[0] = f2bf_bits(w20.x * sv0.x); p2.us[1] = f2bf_bits(w20.y * sv0.y); \
        p2.us[2] = f2bf_bits(w20.z * sv0.z); p2.us[3] = f2bf_bits(w20.w * sv0.w); \
        p2.us[4] = f2bf_bits(w21.x * sv1.x); p2.us[5] = f2bf_bits(w21.y * sv1.y); \
        p2.us[6] = f2bf_bits(w21.z * sv1.z); p2.us[7] = f2bf_bits(w21.w * sv1.w); \
        p3.us[0] = f2bf_bits(w30.x * sv0.x); p3.us[1] = f2bf_bits(w30.y * sv0.y); \
        p3.us[2] = f2bf_bits(w30.z * sv0.z); p3.us[3] = f2bf_bits(w30.w * sv0.w); \
        p3.us[4] = f2bf_bits(w31.x * sv1.x); p3.us[5] = f2bf_bits(w31.y * sv1.y); \
        p3.us[6] = f2bf_bits(w31.z * sv1.z); p3.us[7] = f2bf_bits(w31.w * sv1.w); \
        af0 = p0.v; af1 = p1.v; af2 = p2.v; af3 = p3.v;                        \
    }

    // issue 8 global dword loads for B(T) (each wave-instr: 256B contiguous)
#define SISSUE(T, XR)                                                          \
    {                                                                          \
        const float* xp = xbn + (size_t)(T) * BK * HW;                         \
        _Pragma("unroll")                                                      \
        for (int j = 0; j < 8; ++j) XR[j] = xp[(size_t)j * HW];                \
    }

    // convert + pack + fragment-layout LDS write (1KB contiguous per wave)
#define SWRITE(T, XR)                                                          \
    {                                                                          \
        union { unsigned short us[8]; bf16x8 v; } pk;                          \
        _Pragma("unroll")                                                      \
        for (int j = 0; j < 8; ++j) pk.us[j] = f2bf_bits(XR[j]);               \
        *(bf16x8*)&Bfs[(T) & 1][(kg * 128 + bn) * 8] = pk.v;                   \
    }

#define COMPUTE(BUF)                                                           \
    {                                                                          \
        bf16x8 bfr0 = *(const bf16x8*)&Bfs[BUF][(quad * 128 + wn + l15) * 8];  \
        bf16x8 bfr1 = *(const bf16x8*)&Bfs[BUF][(quad * 128 + wn + 16 + l15) * 8]; \
        acc[0][0] = __builtin_amdgcn_mfma_f32_16x16x32_bf16(af0, bfr0, acc[0][0], 0, 0, 0); \
        acc[0][1] = __builtin_amdgcn_mfma_f32_16x16x32_bf16(af0, bfr1, acc[0][1], 0, 0, 0); \
        acc[1][0] = __builtin_amdgcn_mfma_f32_16x16x32_bf16(af1, bfr0, acc[1][0], 0, 0, 0); \
        acc[1][1] = __builtin_amdgcn_mfma_f32_16x16x32_bf16(af1, bfr1, acc[1][1], 0, 0, 0); \
        acc[2][0] = __builtin_amdgcn_mfma_f32_16x16x32_bf16(af2, bfr0, acc[2][0], 0, 0, 0); \
        acc[2][1] = __builtin_amdgcn_mfma_f32_16x16x32_bf16(af2, bfr1, acc[2][1], 0, 0, 0); \
        acc[3][0] = __builtin_amdgcn_mfma_f32_16x16x32_bf16(af3, bfr0, acc[3][0], 0, 0, 0); \
        acc[3][1] = __builtin_amdgcn_mfma_f32_16x16x32_bf16(af3, bfr1, acc[3][1], 0, 0, 0); \
    }

    // body(it), it <= 13: consumes w-regs(it) [1 iter old], refills for it+1;
    // B(it+2) issued; SWRITE(it+1) consumes regs 1 iter old; only lgkmcnt(0)
    // at the barrier (ds_write publish) -- no vmcnt drain.
#define BODY(IT, XC, XN)                                                       \
    {                                                                          \
        ABUILD()                                                               \
        WLOAD((IT) + 1)                                                        \
        COMPUTE((IT) & 1)                                                      \
        SISSUE((IT) + 2, XN)                                                   \
        SWRITE((IT) + 1, XC)                                                   \
        asm volatile("s_waitcnt lgkmcnt(0)" ::: "memory");                     \
        __builtin_amdgcn_s_barrier();                                          \
    }

    // prologue: tile0 -> Bfs[0]; issue tile1 B; prefetch w(0)
    WLOAD(0)
    SISSUE(0, xa)
    SWRITE(0, xa)
    SISSUE(1, xb)
    asm volatile("s_waitcnt lgkmcnt(0)" ::: "memory");
    __builtin_amdgcn_s_barrier();

    // main loop: it = 0..13  (XC(it) = regs of tile it+1: even->xb, odd->xa)
    #pragma unroll 1
    for (int it2 = 0; it2 < 7; ++it2) {
        const int it = it2 * 2;
        BODY(it,     xb, xa)
        BODY(it + 1, xa, xb)
    }
    // it = 14: no SISSUE(16)
    {
        ABUILD()
        WLOAD(15)
        COMPUTE(0)
        SWRITE(15, xb)
        asm volatile("s_waitcnt lgkmcnt(0)" ::: "memory");
        __builtin_amdgcn_s_barrier();
    }
    // it = 15: compute only
    {
        ABUILD()
        COMPUTE(1)
    }

#undef BODY
#undef COMPUTE
#undef SWRITE
#undef SISSUE
#undef ABUILD
#undef WLOAD

    // epilogue: C/D layout col(n)=l15, row(o)=quad*4+reg
    #pragma unroll
    for (int tm = 0; tm < 4; ++tm) {
        const int o = wm + tm * 16 + quad * 4;
        #pragma unroll
        for (int tn = 0; tn < 2; ++tn) {
            const int n = wn + tn * 16 + l15;
            #pragma unroll
            for (int r = 0; r < 4; ++r)
                outb[(size_t)(o + r) * HW + n] = acc[tm][tn][r];
        }
    }
}

extern "C" void kernel_launch(void* const* d_in, const int* in_sizes, int n_in,
                              void* d_out, int out_size, void* d_ws, size_t ws_size,
                              hipStream_t stream) {
    const float* x      = (const float*)d_in[0];   // (16, 512, 64, 64) fp32
    const float* style  = (const float*)d_in[1];   // (16, 512) fp32
    const float* weight = (const float*)d_in[2];   // (128, 512) fp32
    float* out = (float*)d_out;                    // (16, 128, 64, 64) fp32
    (void)d_ws; (void)ws_size;

    modconv_fused_kernel<<<dim3(NB * 32), dim3(512), 0, stream>>>(x, style, weight, out);
}

// Round 6
// 203.924 us; speedup vs baseline: 1.3041x; 1.3041x over previous
//
#include <hip/hip_runtime.h>
#include <stdint.h>

// B=16, CIN=512, COUT=128, H=W=64
#define NB    16
#define CIN   512
#define COUT  128
#define HW    4096
#define BN    128             // N-tile per block
#define BK    32              // K-tile per iteration
#define NIT   (CIN / BK)      // 16
// grid = 16 b x 32 n-tiles = 512 blocks x 512 thr = 2 blocks/CU

using bf16x8  = __attribute__((ext_vector_type(8))) __bf16;
using floatx4 = __attribute__((ext_vector_type(4))) float;

// RNE float -> bf16 bits (proven in previous session)
__device__ __forceinline__ unsigned short f2bf_bits(float f) {
    union { float f; unsigned u; } v; v.f = f;
    return (unsigned short)((v.u + 0x7fffu + ((v.u >> 16) & 1u)) >> 16);
}

// ---------------------------------------------------------------------------
// Single fused kernel = R4's proven pipeline with the A-DMA replaced by an
// LDS-staged A-build:
//   * per iter, each thread computes 8 A elements (no redundancy):
//     thread t covers m = t>>2, k-chunk (t&3)*8 of the 128x32 weight slice,
//     loads 32B of weight (coalesced, L2-resident) + 32B of style (L1
//     broadcast), converts w*s -> bf16 once, one ds_write_b128 into the
//     [k8][m][j] fragment layout (same layout R4's COMPUTE already reads).
//   * weight/style/x loads all issued ONE FULL ITERATION ahead into
//     dedicated register sets -> compiler-inserted vmcnt waits never stall;
//     barrier needs only lgkmcnt(0). No global_load_lds, no vmcnt drains.
// Deletes: modw kernel, its graph-node gap, and the 4 MB mw round-trip.
// ---------------------------------------------------------------------------
__global__ __launch_bounds__(512, 4)
void modconv_fused_kernel(const float* __restrict__ x,
                          const float* __restrict__ style,
                          const float* __restrict__ weight,
                          float* __restrict__ out)
{
    __shared__ __align__(16) __bf16 Alds[2][4 * 128 * 8];  // [k8][m][j] 2 x 8 KB
    __shared__ __align__(16) __bf16 Bfs[2][4 * 128 * 8];   // [kg][n][j] 2 x 8 KB

    const int tid  = threadIdx.x;
    const int lane = tid & 63;
    const int wave = tid >> 6;          // 0..7
    const int quad = lane >> 4;
    const int l15  = lane & 15;

    const int b  = blockIdx.x >> 5;
    const int n0 = (blockIdx.x & 31) * BN;

    float* outb = out + (size_t)b * COUT * HW + n0;

    const int wm = (wave & 1) * 64;     // wave tile 64(m) x 32(n)
    const int wn = (wave >> 1) * 32;

    // A staging geometry: thread t -> m = t>>2, k-chunk (t&3)*8
    const int am  = tid >> 2;           // 0..127
    const int ak8 = tid & 3;            // 0..3
    const float* wrow = weight + (size_t)am * CIN + ak8 * 8;
    const float* srow = style + (size_t)b * CIN + ak8 * 8;
    // LDS element offset for this thread's bf16x8: (k8*128 + m)*8
    const int aoff = (ak8 * 128 + am) * 8;

    // B staging geometry: thread covers kg = tid>>7 (k-slab of 8), bn = tid&127
    const int kg = tid >> 7;            // 0..3
    const int bn = tid & 127;           // n within tile
    const float* xbn = x + (size_t)b * CIN * HW + (size_t)kg * 8 * HW + n0 + bn;

    floatx4 acc[4][2];
    #pragma unroll
    for (int i = 0; i < 4; ++i)
        #pragma unroll
        for (int j = 0; j < 2; ++j)
            acc[i][j] = (floatx4){0.f, 0.f, 0.f, 0.f};

    // prefetch register sets (two each, hand-rotated: no runtime indexing)
    float  xa[8], xb[8];
    float4 wa0, wa1, sa0, sa1;
    float4 wb0, wb1, sb0, sb1;

    // issue weight+style loads for tile T (4x float4; 1 iter of latency slack)
#define WISSUE(T, W0, W1, S0, S1)                                              \
    {                                                                          \
        const int ko = (T) * BK;                                               \
        W0 = *(const float4*)(wrow + ko); W1 = *(const float4*)(wrow + ko + 4);\
        S0 = *(const float4*)(srow + ko); S1 = *(const float4*)(srow + ko + 4);\
    }

    // build + write this thread's 8 A elements (fragment layout, 1x b128)
#define AWRITE(T, W0, W1, S0, S1)                                              \
    {                                                                          \
        union { unsigned short us[8]; bf16x8 v; } pk;                          \
        pk.us[0] = f2bf_bits(W0.x * S0.x); pk.us[1] = f2bf_bits(W0.y * S0.y);  \
        pk.us[2] = f2bf_bits(W0.z * S0.z); pk.us[3] = f2bf_bits(W0.w * S0.w);  \
        pk.us[4] = f2bf_bits(W1.x * S1.x); pk.us[5] = f2bf_bits(W1.y * S1.y);  \
        pk.us[6] = f2bf_bits(W1.z * S1.z); pk.us[7] = f2bf_bits(W1.w * S1.w);  \
        *(bf16x8*)&Alds[(T) & 1][aoff] = pk.v;                                 \
    }

    // issue 8 global dword loads for B(T) (each wave-instr: 256B contiguous)
#define SISSUE(T, XR)                                                          \
    {                                                                          \
        const float* xp = xbn + (size_t)(T) * BK * HW;                         \
        _Pragma("unroll")                                                      \
        for (int j = 0; j < 8; ++j) XR[j] = xp[(size_t)j * HW];                \
    }

    // convert + pack + fragment-layout LDS write (1KB contiguous per wave)
#define SWRITE(T, XR)                                                          \
    {                                                                          \
        union { unsigned short us[8]; bf16x8 v; } pk;                          \
        _Pragma("unroll")                                                      \
        for (int j = 0; j < 8; ++j) pk.us[j] = f2bf_bits(XR[j]);               \
        *(bf16x8*)&Bfs[(T) & 1][(kg * 128 + bn) * 8] = pk.v;                   \
    }

#define COMPUTE(BUF)                                                           \
    {                                                                          \
        bf16x8 af[4];                                                          \
        _Pragma("unroll")                                                      \
        for (int tm = 0; tm < 4; ++tm)                                         \
            af[tm] = *(const bf16x8*)&Alds[BUF][(quad * 128 + wm + tm * 16 + l15) * 8]; \
        bf16x8 bfr[2];                                                         \
        _Pragma("unroll")                                                      \
        for (int tn = 0; tn < 2; ++tn)                                         \
            bfr[tn] = *(const bf16x8*)&Bfs[BUF][(quad * 128 + wn + tn * 16 + l15) * 8]; \
        _Pragma("unroll")                                                      \
        for (int tm = 0; tm < 4; ++tm)                                         \
            _Pragma("unroll")                                                  \
            for (int tn = 0; tn < 2; ++tn)                                     \
                acc[tm][tn] = __builtin_amdgcn_mfma_f32_16x16x32_bf16(         \
                    af[tm], bfr[tn], acc[tm][tn], 0, 0, 0);                    \
    }

    // body(it), it <= 13: COMPUTE reads buf it&1; loads for it+2 issued;
    // writes publish tile it+1 into buf (it+1)&1 (whose last reads were at
    // it-1, sealed by the previous barrier). Only lgkmcnt(0) at the barrier.
#define BODY(IT, XC, XN, WC0, WC1, SC0, SC1, WN0, WN1, SN0, SN1)               \
    {                                                                          \
        COMPUTE((IT) & 1)                                                      \
        WISSUE((IT) + 2, WN0, WN1, SN0, SN1)                                   \
        SISSUE((IT) + 2, XN)                                                   \
        AWRITE((IT) + 1, WC0, WC1, SC0, SC1)                                   \
        SWRITE((IT) + 1, XC)                                                   \
        asm volatile("s_waitcnt lgkmcnt(0)" ::: "memory");                     \
        __builtin_amdgcn_s_barrier();                                          \
    }

    // prologue: tile0 -> buf0; issue tile1 loads
    WISSUE(0, wa0, wa1, sa0, sa1)
    SISSUE(0, xa)
    AWRITE(0, wa0, wa1, sa0, sa1)
    SWRITE(0, xa)
    WISSUE(1, wb0, wb1, sb0, sb1)
    SISSUE(1, xb)
    asm volatile("s_waitcnt lgkmcnt(0)" ::: "memory");
    __builtin_amdgcn_s_barrier();

    // main loop: it = 0..13 (even: consume b-sets, refill a-sets; odd: vice versa)
    #pragma unroll 1
    for (int it2 = 0; it2 < 7; ++it2) {
        const int it = it2 * 2;
        BODY(it,     xb, xa, wb0, wb1, sb0, sb1, wa0, wa1, sa0, sa1)
        BODY(it + 1, xa, xb, wa0, wa1, sa0, sa1, wb0, wb1, sb0, sb1)
    }
    // it = 14: no issue of tile 16
    {
        COMPUTE(0)
        AWRITE(15, wb0, wb1, sb0, sb1)
        SWRITE(15, xb)
        asm volatile("s_waitcnt lgkmcnt(0)" ::: "memory");
        __builtin_amdgcn_s_barrier();
    }
    // it = 15: compute only
    COMPUTE(1)

#undef BODY
#undef COMPUTE
#undef SWRITE
#undef SISSUE
#undef AWRITE
#undef WISSUE

    // epilogue: C/D layout col(n)=l15, row(o)=quad*4+reg
    #pragma unroll
    for (int tm = 0; tm < 4; ++tm) {
        const int o = wm + tm * 16 + quad * 4;
        #pragma unroll
        for (int tn = 0; tn < 2; ++tn) {
            const int n = wn + tn * 16 + l15;
            #pragma unroll
            for (int r = 0; r < 4; ++r)
                outb[(size_t)(o + r) * HW + n] = acc[tm][tn][r];
        }
    }
}

extern "C" void kernel_launch(void* const* d_in, const int* in_sizes, int n_in,
                              void* d_out, int out_size, void* d_ws, size_t ws_size,
                              hipStream_t stream) {
    const float* x      = (const float*)d_in[0];   // (16, 512, 64, 64) fp32
    const float* style  = (const float*)d_in[1];   // (16, 512) fp32
    const float* weight = (const float*)d_in[2];   // (128, 512) fp32
    float* out = (float*)d_out;                    // (16, 128, 64, 64) fp32
    (void)d_ws; (void)ws_size;

    modconv_fused_kernel<<<dim3(NB * 32), dim3(512), 0, stream>>>(x, style, weight, out);
}